// Round 11
// baseline (1090.643 us; speedup 1.0000x reference)
//
#include <hip/hip_runtime.h>
#include <hip/hip_bf16.h>

typedef __attribute__((ext_vector_type(8))) short short8;   // 8 bf16 in 4 VGPRs
typedef __attribute__((ext_vector_type(4))) float f32x4;

#define MFMA_B16(a,b,c) __builtin_amdgcn_mfma_f32_16x16x32_bf16((a),(b),(c),0,0,0)

namespace {
constexpr int B_SZ = 2048;
constexpr int S_SZ = 200;
constexpr int SPAD = 208;      // 13 row tiles of 16
constexpr int NRT  = 13;
constexpr int INQ  = 120;
constexpr int HID  = 512;

// LDS byte offsets
constexpr int L_XF    = 0;        // X fragments: 13*4*64*8 bf16 = 53248 B
constexpr int L_WT1   = 53248;    // Wk frags   : 32768 B
constexpr int L_WT2   = 86016;    // Wkc frags  : 32768 B
constexpr int L_QV    = 118784;   // q vector   : 128 f32
constexpr int L_X0    = 119296;   // x row 0    : 128 f32
constexpr int L_QP    = 119808;   // q partials : 4*128*2 f32 = 4096 B
constexpr int L_PROBS = 123904;   // scores/probs: 8*208 f32 = 6656 B
constexpr int L_DEN   = 130560;   // 8 f32
constexpr int L_STATS = 130592;   // 16*8*2 f32 = 1024 B
constexpr int L_MU    = 131616;   // 16 f32
constexpr int L_RS    = 131680;   // 16 f32
constexpr int L_TOTAL = 131744;
}

// round-to-nearest-even f32 -> bf16 bits
static __device__ __forceinline__ short f2bf(float x) {
    unsigned u = __builtin_bit_cast(unsigned, x);
    u = (u + 0x7FFFu + ((u >> 16) & 1u)) >> 16;
    return (short)u;
}
static __device__ __forceinline__ float sigm(float x) { return 1.f / (1.f + __expf(-x)); }

__global__ void __launch_bounds__(512)
attseq_main(const int* __restrict__ posid, const float* __restrict__ qcv,
            const float* __restrict__ maskp, const float* __restrict__ posembed,
            const float* __restrict__ Wq, const float* __restrict__ bq,
            const float* __restrict__ Wqc, const float* __restrict__ bqc,
            const float* __restrict__ Wk, const float* __restrict__ bk,
            const float* __restrict__ Wkc, const float* __restrict__ bkc,
            const float* __restrict__ Wv, const float* __restrict__ bv,
            const float* __restrict__ Wvc, const float* __restrict__ bvc,
            const float* __restrict__ lng, const float* __restrict__ lnb,
            float* __restrict__ out)      // *** f32 output: reference returns float32 ***
{
    extern __shared__ __align__(16) char smem[];
    const int b = blockIdx.x;
    const int t = threadIdx.x;
    const int w = t >> 6;        // wave 0..7
    const int l = t & 63;
    const int g = l >> 4;        // 16-lane group 0..3
    const int d = l & 15;

    const f32x4 fzero = {0.f, 0.f, 0.f, 0.f};

    // ---- P0: build X fragments in LDS (bf16), x row 0 in f32 ----
    // A-frag: tile (rt,kt); element (row r, k_local) at lane r+16*(k_local>>3), elem k_local&7
    {
        short* xfb = (short*)(smem + L_XF);
        float* x0f = (float*)(smem + L_X0);
        for (int it = 0; it < 52; ++it) {
            int idx = t + (it << 9);          // 0..26623 over (s 0..207, c 0..127)
            int s = idx >> 7, c = idx & 127;
            float val = 0.f;
            if (s < S_SZ) {
                if (c < INQ) val = qcv[(size_t)b * (S_SZ * INQ) + s * INQ + c];
                else {
                    int pid = posid[b * S_SZ + s];
                    val = posembed[pid * 8 + (c - INQ)];
                }
            }
            if (s == 0) x0f[c] = val;
            int rt = s >> 4, r = s & 15, kt = c >> 5, ck = c & 31;
            int off = ((rt * 4 + kt) * 64 + (r + 16 * (ck >> 3))) * 8 + (ck & 7);
            xfb[off] = f2bf(val);
        }
    }
    // ---- P2: stage Wk/Wkc fragments into LDS from global f32 ----
    {
        short* wt1 = (short*)(smem + L_WT1);
        short* wt2 = (short*)(smem + L_WT2);
        for (int i = 0; i < 32; ++i) {
            int e = t + (i << 9);             // 0..16383 over (k 0..127, n 0..127)
            int k = e >> 7, n = e & 127;
            int ct = n >> 4, kt = k >> 5, g2 = (k >> 3) & 3, j = k & 7;
            int off = ((ct * 4 + kt) * 64 + (16 * g2 + (n & 15))) * 8 + j;
            wt1[off] = f2bf(Wk[e]);
            wt2[off] = f2bf(Wkc[e]);
        }
    }
    __syncthreads();

    // ---- P1a: q projection partials (f32 exact path) ----
    {
        int j = t & 127, qt = t >> 7;
        const float* x0 = (const float*)(smem + L_X0);
        float h1 = 0.f, h1c = 0.f;
        for (int i = 32 * qt; i < 32 * qt + 32; ++i) {
            float xv = x0[i];
            h1  += xv * Wq[i * 128 + j];
            h1c += xv * Wqc[i * 128 + j];
        }
        float* qp = (float*)(smem + L_QP);
        qp[(qt * 128 + j) * 2 + 0] = h1;
        qp[(qt * 128 + j) * 2 + 1] = h1c;
    }
    __syncthreads();
    if (t < 128) {
        const float* qp = (const float*)(smem + L_QP);
        float h1 = 0.f, h1c = 0.f;
        #pragma unroll
        for (int qt = 0; qt < 4; ++qt) {
            h1  += qp[(qt * 128 + t) * 2 + 0];
            h1c += qp[(qt * 128 + t) * 2 + 1];
        }
        h1 += bq[t]; h1c += bqc[t];
        ((float*)(smem + L_QV))[t] = h1 * sigm(h1c);
    }
    __syncthreads();

    // ---- P3: K projection (MFMA) + raw scores ----
    {
        const float* qv = (const float*)(smem + L_QV);
        float* sc = (float*)(smem + L_PROBS);
        float bkv[8], bkcv[8];
        #pragma unroll
        for (int ct = 0; ct < 8; ++ct) { bkv[ct] = bk[ct * 16 + d]; bkcv[ct] = bkc[ct * 16 + d]; }
        for (int rt = w; rt < NRT; rt += 8) {
            short8 a[4];
            #pragma unroll
            for (int kt = 0; kt < 4; ++kt)
                a[kt] = *(const short8*)(smem + L_XF + (((rt * 4 + kt) * 64 + l) << 4));
            f32x4 acc1[8], acc2[8];
            #pragma unroll
            for (int ct = 0; ct < 8; ++ct) { acc1[ct] = fzero; acc2[ct] = fzero; }
            #pragma unroll
            for (int kt = 0; kt < 4; ++kt) {
                #pragma unroll
                for (int ct = 0; ct < 8; ++ct) {
                    short8 b1 = *(const short8*)(smem + L_WT1 + (((ct * 4 + kt) * 64 + l) << 4));
                    short8 b2 = *(const short8*)(smem + L_WT2 + (((ct * 4 + kt) * 64 + l) << 4));
                    acc1[ct] = MFMA_B16(a[kt], b1, acc1[ct]);
                    acc2[ct] = MFMA_B16(a[kt], b2, acc2[ct]);
                }
            }
            // doc-D layout (HW-confirmed): acc[r] = K[row = rt*16+4g+r][chan = ct*16+d]
            #pragma unroll
            for (int ct = 0; ct < 8; ++ct) {
                float qd = qv[ct * 16 + d];
                #pragma unroll
                for (int r = 0; r < 4; ++r) {
                    float h1  = acc1[ct][r] + bkv[ct];
                    float h1c = acc2[ct][r] + bkcv[ct];
                    float p = qd * (h1 * sigm(h1c));
                    p += __shfl_xor(p, 1); p += __shfl_xor(p, 2);
                    p += __shfl_xor(p, 4); p += __shfl_xor(p, 8);
                    if (d == 0) {
                        int row = rt * 16 + 4 * g + r;
                        sc[ct * SPAD + row] = (row < S_SZ)
                            ? (p + (1.f - maskp[row]) * (-10000.f)) * 0.25f
                            : -1e30f;
                    }
                }
            }
        }
    }
    __syncthreads();

    // ---- P4: softmax per head (wave w <-> head w), store unnormalized exp ----
    {
        float* sc = (float*)(smem + L_PROBS);
        float s0 = sc[w * SPAD + l];
        float s1 = sc[w * SPAD + l + 64];
        float s2 = sc[w * SPAD + l + 128];
        float s3 = (l < 16) ? sc[w * SPAD + l + 192] : -1e30f;
        float m = fmaxf(fmaxf(s0, s1), fmaxf(s2, s3));
        #pragma unroll
        for (int mk = 1; mk < 64; mk <<= 1) m = fmaxf(m, __shfl_xor(m, mk));
        float p0 = __expf(s0 - m), p1 = __expf(s1 - m), p2 = __expf(s2 - m);
        float p3 = (l < 16) ? __expf(s3 - m) : 0.f;
        float sum = p0 + p1 + p2 + p3;
        #pragma unroll
        for (int mk = 1; mk < 64; mk <<= 1) sum += __shfl_xor(sum, mk);
        sc[w * SPAD + l]       = p0;
        sc[w * SPAD + l + 64]  = p1;
        sc[w * SPAD + l + 128] = p2;
        if (l < 16) sc[w * SPAD + l + 192] = p3;
        if (l == 0) ((float*)(smem + L_DEN))[w] = sum;
    }
    __syncthreads();

    // ---- P5: V projection (MFMA) + LayerNorm + weighted accumulate ----
    {
        // persistent B-fragments for head w's 64 columns, gathered from global f32
        short8 fv[4][4], fvc[4][4];
        {
            const float* wv0  = Wv  + (size_t)(8 * (l >> 4)) * HID + 64 * w + d;
            const float* wvc0 = Wvc + (size_t)(8 * (l >> 4)) * HID + 64 * w + d;
            #pragma unroll
            for (int cc = 0; cc < 4; ++cc) {
                #pragma unroll
                for (int kt = 0; kt < 4; ++kt) {
                    #pragma unroll
                    for (int j = 0; j < 8; ++j) {
                        int o = (32 * kt + j) * HID + 16 * cc;
                        fv[cc][kt][j]  = f2bf(wv0[o]);
                        fvc[cc][kt][j] = f2bf(wvc0[o]);
                    }
                }
            }
        }
        float bvv[4], bvcv[4], gv[4], bbv[4];
        #pragma unroll
        for (int cc = 0; cc < 4; ++cc) {
            int c = 64 * w + 16 * cc + d;
            bvv[cc] = bv[c]; bvcv[cc] = bvc[c]; gv[cc] = lng[c]; bbv[cc] = lnb[c];
        }
        float ctx[4] = {0.f, 0.f, 0.f, 0.f};
        const float* pr = (const float*)(smem + L_PROBS);
        float* stats = (float*)(smem + L_STATS);
        float* muR = (float*)(smem + L_MU);
        float* rsR = (float*)(smem + L_RS);

        for (int rt = 0; rt < NRT; ++rt) {
            short8 a[4];
            #pragma unroll
            for (int kt = 0; kt < 4; ++kt)
                a[kt] = *(const short8*)(smem + L_XF + (((rt * 4 + kt) * 64 + l) << 4));
            f32x4 acc1[4], acc2[4];
            #pragma unroll
            for (int cc = 0; cc < 4; ++cc) { acc1[cc] = fzero; acc2[cc] = fzero; }
            #pragma unroll
            for (int kt = 0; kt < 4; ++kt) {
                #pragma unroll
                for (int cc = 0; cc < 4; ++cc) {
                    acc1[cc] = MFMA_B16(a[kt], fv[cc][kt],  acc1[cc]);
                    acc2[cc] = MFMA_B16(a[kt], fvc[cc][kt], acc2[cc]);
                }
            }
            float vout[4][4];
            #pragma unroll
            for (int cc = 0; cc < 4; ++cc)
                #pragma unroll
                for (int r = 0; r < 4; ++r)
                    vout[cc][r] = (acc1[cc][r] + bvv[cc]) * sigm(acc2[cc][r] + bvcv[cc]);
            // per-row partial LN stats over this wave's 64 cols
            #pragma unroll
            for (int r = 0; r < 4; ++r) {
                float s1 = vout[0][r] + vout[1][r] + vout[2][r] + vout[3][r];
                float s2 = vout[0][r] * vout[0][r] + vout[1][r] * vout[1][r]
                         + vout[2][r] * vout[2][r] + vout[3][r] * vout[3][r];
                #pragma unroll
                for (int mk = 1; mk <= 8; mk <<= 1) {
                    s1 += __shfl_xor(s1, mk);
                    s2 += __shfl_xor(s2, mk);
                }
                if (d == 0) {
                    int rl = 4 * g + r;
                    stats[(rl * 8 + w) * 2 + 0] = s1;
                    stats[(rl * 8 + w) * 2 + 1] = s2;
                }
            }
            __syncthreads();
            if (t < 16) {
                float s1 = 0.f, s2 = 0.f;
                #pragma unroll
                for (int ww = 0; ww < 8; ++ww) {
                    s1 += stats[(t * 8 + ww) * 2 + 0];
                    s2 += stats[(t * 8 + ww) * 2 + 1];
                }
                float mu = s1 * (1.f / 512.f);
                float var = s2 * (1.f / 512.f) - mu * mu;
                muR[t] = mu;
                rsR[t] = rsqrtf(var + 1e-5f);
            }
            __syncthreads();
            #pragma unroll
            for (int r = 0; r < 4; ++r) {
                int rl = 4 * g + r;
                float mu = muR[rl], rs = rsR[rl];
                float pw = pr[w * SPAD + rt * 16 + rl];
                #pragma unroll
                for (int cc = 0; cc < 4; ++cc)
                    ctx[cc] += pw * ((vout[cc][r] - mu) * rs * gv[cc] + bbv[cc]);
            }
        }
        // reduce over row-groups g (lanes ^16, ^32), then write f32
        #pragma unroll
        for (int cc = 0; cc < 4; ++cc) {
            ctx[cc] += __shfl_xor(ctx[cc], 16);
            ctx[cc] += __shfl_xor(ctx[cc], 32);
        }
        float invden = 1.f / ((const float*)(smem + L_DEN))[w];
        if (l < 16) {
            #pragma unroll
            for (int cc = 0; cc < 4; ++cc) {
                int c = 64 * w + 16 * cc + l;
                out[(size_t)b * HID + c] = ctx[cc] * invden;   // f32 store
            }
        }
    }
}

extern "C" void kernel_launch(void* const* d_in, const int* in_sizes, int n_in,
                              void* d_out, int out_size, void* d_ws, size_t ws_size,
                              hipStream_t stream)
{
    const int*   posid = (const int*)d_in[0];
    const float* qcv   = (const float*)d_in[1];
    const float* mask  = (const float*)d_in[2];
    const float* pe    = (const float*)d_in[3];
    const float* Wq    = (const float*)d_in[4];
    const float* bq    = (const float*)d_in[5];
    const float* Wqc   = (const float*)d_in[6];
    const float* bqc   = (const float*)d_in[7];
    const float* Wk    = (const float*)d_in[8];
    const float* bk    = (const float*)d_in[9];
    const float* Wkc   = (const float*)d_in[10];
    const float* bkc   = (const float*)d_in[11];
    const float* Wv    = (const float*)d_in[12];
    const float* bv    = (const float*)d_in[13];
    const float* Wvc   = (const float*)d_in[14];
    const float* bvc   = (const float*)d_in[15];
    const float* lng   = (const float*)d_in[16];
    const float* lnb   = (const float*)d_in[17];
    float* outp = (float*)d_out;     // reference output dtype is float32

    hipFuncSetAttribute((const void*)attseq_main,
                        hipFuncAttributeMaxDynamicSharedMemorySize, L_TOTAL);

    attseq_main<<<B_SZ, 512, L_TOTAL, stream>>>(posid, qcv, mask, pe, Wq, bq, Wqc, bqc,
                                                Wk, bk, Wkc, bkc, Wv, bv, Wvc, bvc,
                                                lng, lnb, outp);
}

// Round 12
// 1047.582 us; speedup vs baseline: 1.0411x; 1.0411x over previous
//
#include <hip/hip_runtime.h>
#include <hip/hip_bf16.h>

typedef __attribute__((ext_vector_type(8))) short short8;   // 8 bf16 in 4 VGPRs
typedef __attribute__((ext_vector_type(4))) float f32x4;

#define MFMA_B16(a,b,c) __builtin_amdgcn_mfma_f32_16x16x32_bf16((a),(b),(c),0,0,0)

namespace {
constexpr int B_SZ = 2048;
constexpr int S_SZ = 200;
constexpr int SPAD = 208;      // 13 row tiles of 16
constexpr int NRT  = 13;
constexpr int INQ  = 120;
constexpr int HID  = 512;

// LDS byte offsets (alias: QP region reused by WST/MU/RS in P5)
constexpr int L_XF    = 0;        // X fragments: 13*4*64*8 bf16 = 53248 B
constexpr int L_PROBS = 53248;    // scores/probs: 8*208*4 = 6656 B
constexpr int L_QV    = 59904;    // q vector: 128 f32 = 512 B
constexpr int L_X0    = 60416;    // x row 0 : 128 f32 = 512 B
constexpr int L_QP    = 60928;    // q partials: 4*128*2*4 = 4096 B   (P1 only)
constexpr int L_WST   = 60928;    // LN stats  : 200*8*2*4 = 12800 B  (P5 only)
constexpr int L_MU    = 73728;    // 200*4 = 800
constexpr int L_RS    = 74528;    // 200*4 = 800
constexpr int L_TOTAL = 75328;    // 2 blocks/CU (<= 80 KB)
}

// round-to-nearest-even f32 -> bf16 bits
static __device__ __forceinline__ short f2bf(float x) {
    unsigned u = __builtin_bit_cast(unsigned, x);
    u = (u + 0x7FFFu + ((u >> 16) & 1u)) >> 16;
    return (short)u;
}
static __device__ __forceinline__ float sigm(float x) { return 1.f / (1.f + __expf(-x)); }

__global__ void __launch_bounds__(512, 4)   // cap VGPR at 128 -> 2 blocks/CU
attseq_main(const int* __restrict__ posid, const float* __restrict__ qcv,
            const float* __restrict__ maskp, const float* __restrict__ posembed,
            const float* __restrict__ Wq, const float* __restrict__ bq,
            const float* __restrict__ Wqc, const float* __restrict__ bqc,
            const float* __restrict__ Wk, const float* __restrict__ bk,
            const float* __restrict__ Wkc, const float* __restrict__ bkc,
            const float* __restrict__ Wv, const float* __restrict__ bv,
            const float* __restrict__ Wvc, const float* __restrict__ bvc,
            const float* __restrict__ lng, const float* __restrict__ lnb,
            float* __restrict__ out)
{
    extern __shared__ __align__(16) char smem[];
    const int b = blockIdx.x;
    const int t = threadIdx.x;
    const int w = t >> 6;        // wave 0..7  <-> head w
    const int l = t & 63;
    const int g = l >> 4;        // 16-lane group 0..3
    const int d = l & 15;

    const f32x4 fzero = {0.f, 0.f, 0.f, 0.f};

    // ---- P0: build X fragments in LDS (bf16), x row 0 in f32 ----
    {
        short* xfb = (short*)(smem + L_XF);
        float* x0f = (float*)(smem + L_X0);
        for (int it = 0; it < 52; ++it) {
            int idx = t + (it << 9);          // (s 0..207, c 0..127)
            int s = idx >> 7, c = idx & 127;
            float val = 0.f;
            if (s < S_SZ) {
                if (c < INQ) val = qcv[(size_t)b * (S_SZ * INQ) + s * INQ + c];
                else {
                    int pid = posid[b * S_SZ + s];
                    val = posembed[pid * 8 + (c - INQ)];
                }
            }
            if (s == 0) x0f[c] = val;
            int rt = s >> 4, r = s & 15, kt = c >> 5, ck = c & 31;
            int off = ((rt * 4 + kt) * 64 + (r + 16 * (ck >> 3))) * 8 + (ck & 7);
            xfb[off] = f2bf(val);
        }
    }
    __syncthreads();

    // ---- P1a: q projection partials (f32 exact path) ----
    {
        int j = t & 127, qt = t >> 7;
        const float* x0 = (const float*)(smem + L_X0);
        float h1 = 0.f, h1c = 0.f;
        for (int i = 32 * qt; i < 32 * qt + 32; ++i) {
            float xv = x0[i];
            h1  += xv * Wq[i * 128 + j];
            h1c += xv * Wqc[i * 128 + j];
        }
        float* qp = (float*)(smem + L_QP);
        qp[(qt * 128 + j) * 2 + 0] = h1;
        qp[(qt * 128 + j) * 2 + 1] = h1c;
    }
    __syncthreads();
    // ---- P1b: finish q (t<128); all threads gather K-frags from global ----
    if (t < 128) {
        const float* qp = (const float*)(smem + L_QP);
        float h1 = 0.f, h1c = 0.f;
        #pragma unroll
        for (int qt = 0; qt < 4; ++qt) {
            h1  += qp[(qt * 128 + t) * 2 + 0];
            h1c += qp[(qt * 128 + t) * 2 + 1];
        }
        h1 += bq[t]; h1c += bqc[t];
        ((float*)(smem + L_QV))[t] = h1 * sigm(h1c);
    }
    short8 fk[4], fkc[4];      // wave w's head: cols w*16+d, k = 32kt+8*(l>>4)+j
    {
        const float* wk0  = Wk  + (size_t)(8 * (l >> 4)) * 128 + w * 16 + d;
        const float* wkc0 = Wkc + (size_t)(8 * (l >> 4)) * 128 + w * 16 + d;
        #pragma unroll
        for (int kt = 0; kt < 4; ++kt)
            #pragma unroll
            for (int j = 0; j < 8; ++j) {
                int o = (32 * kt + j) * 128;
                fk[kt][j]  = f2bf(wk0[o]);
                fkc[kt][j] = f2bf(wkc0[o]);
            }
    }
    __syncthreads();

    // ---- P3: K projection (per-head MFMA) + raw scores ----
    {
        const float* qv = (const float*)(smem + L_QV);
        float* sc = (float*)(smem + L_PROBS);
        const float qd = qv[w * 16 + d];
        const float bkd = bk[w * 16 + d], bkcd = bkc[w * 16 + d];
        for (int rt = 0; rt < NRT; ++rt) {
            short8 a[4];
            #pragma unroll
            for (int kt = 0; kt < 4; ++kt)
                a[kt] = *(const short8*)(smem + L_XF + (((rt * 4 + kt) * 64 + l) << 4));
            f32x4 acc1 = fzero, acc2 = fzero;
            #pragma unroll
            for (int kt = 0; kt < 4; ++kt) {
                acc1 = MFMA_B16(a[kt], fk[kt],  acc1);
                acc2 = MFMA_B16(a[kt], fkc[kt], acc2);
            }
            // doc-D: acc[r] = K[row = rt*16+4g+r][chan = w*16+d]
            #pragma unroll
            for (int r = 0; r < 4; ++r) {
                float h1  = acc1[r] + bkd;
                float h1c = acc2[r] + bkcd;
                float p = qd * (h1 * sigm(h1c));
                p += __shfl_xor(p, 1); p += __shfl_xor(p, 2);
                p += __shfl_xor(p, 4); p += __shfl_xor(p, 8);
                if (d == 0) {
                    int row = rt * 16 + 4 * g + r;
                    sc[w * SPAD + row] = (row < S_SZ)
                        ? (p + (1.f - maskp[row]) * (-10000.f)) * 0.25f
                        : -1e30f;
                }
            }
        }
    }
    __syncthreads();

    // ---- P4: softmax per head (wave w), store NORMALIZED probs ----
    {
        float* sc = (float*)(smem + L_PROBS);
        float s0 = sc[w * SPAD + l];
        float s1 = sc[w * SPAD + l + 64];
        float s2 = sc[w * SPAD + l + 128];
        float s3 = (l < 16) ? sc[w * SPAD + l + 192] : -1e30f;
        float m = fmaxf(fmaxf(s0, s1), fmaxf(s2, s3));
        #pragma unroll
        for (int mk = 1; mk < 64; mk <<= 1) m = fmaxf(m, __shfl_xor(m, mk));
        float p0 = __expf(s0 - m), p1 = __expf(s1 - m), p2 = __expf(s2 - m);
        float p3 = (l < 16) ? __expf(s3 - m) : 0.f;
        float sum = p0 + p1 + p2 + p3;
        #pragma unroll
        for (int mk = 1; mk < 64; mk <<= 1) sum += __shfl_xor(sum, mk);
        float inv = 1.f / sum;
        sc[w * SPAD + l]       = p0 * inv;
        sc[w * SPAD + l + 64]  = p1 * inv;
        sc[w * SPAD + l + 128] = p2 * inv;
        if (l < 16) sc[w * SPAD + l + 192] = p3 * inv;
    }
    __syncthreads();

    // ---- P5 phase A: V projection, accumulate LN stats (no barriers inside) ----
    {
        float* wst = (float*)(smem + L_WST);
        for (int cc = 0; cc < 4; ++cc) {
            short8 fv[4], fvc[4];
            const float* wv0  = Wv  + (size_t)(8 * (l >> 4)) * HID + 64 * w + 16 * cc + d;
            const float* wvc0 = Wvc + (size_t)(8 * (l >> 4)) * HID + 64 * w + 16 * cc + d;
            #pragma unroll
            for (int kt = 0; kt < 4; ++kt)
                #pragma unroll
                for (int j = 0; j < 8; ++j) {
                    int o = (32 * kt + j) * HID;
                    fv[kt][j]  = f2bf(wv0[o]);
                    fvc[kt][j] = f2bf(wvc0[o]);
                }
            const float bvn  = bv[64 * w + 16 * cc + d];
            const float bvcn = bvc[64 * w + 16 * cc + d];
            for (int rt = 0; rt < NRT; ++rt) {
                short8 a[4];
                #pragma unroll
                for (int kt = 0; kt < 4; ++kt)
                    a[kt] = *(const short8*)(smem + L_XF + (((rt * 4 + kt) * 64 + l) << 4));
                f32x4 acc1 = fzero, acc2 = fzero;
                #pragma unroll
                for (int kt = 0; kt < 4; ++kt) {
                    acc1 = MFMA_B16(a[kt], fv[kt],  acc1);
                    acc2 = MFMA_B16(a[kt], fvc[kt], acc2);
                }
                #pragma unroll
                for (int r = 0; r < 4; ++r) {
                    float vout = (acc1[r] + bvn) * sigm(acc2[r] + bvcn);
                    float s1 = vout, s2 = vout * vout;
                    #pragma unroll
                    for (int mk = 1; mk <= 8; mk <<= 1) {
                        s1 += __shfl_xor(s1, mk);
                        s2 += __shfl_xor(s2, mk);
                    }
                    if (d == 0) {
                        int row = rt * 16 + 4 * g + r;
                        if (row < S_SZ) {
                            int o2 = (row * 8 + w) * 2;
                            if (cc == 0) { wst[o2] = s1;  wst[o2 + 1] = s2; }
                            else         { wst[o2] += s1; wst[o2 + 1] += s2; }
                        }
                    }
                }
            }
        }
    }
    __syncthreads();
    // ---- finalize LN stats for 200 rows ----
    if (t < S_SZ) {
        const float* wst = (const float*)(smem + L_WST);
        float s1 = 0.f, s2 = 0.f;
        #pragma unroll
        for (int ww = 0; ww < 8; ++ww) {
            s1 += wst[(t * 8 + ww) * 2 + 0];
            s2 += wst[(t * 8 + ww) * 2 + 1];
        }
        float mu = s1 * (1.f / 512.f);
        float var = s2 * (1.f / 512.f) - mu * mu;
        ((float*)(smem + L_MU))[t] = mu;
        ((float*)(smem + L_RS))[t] = rsqrtf(var + 1e-5f);
    }
    __syncthreads();

    // ---- P5 phase B: recompute V, apply LN, weighted accumulate, write ----
    {
        const float* pr  = (const float*)(smem + L_PROBS);
        const float* muR = (const float*)(smem + L_MU);
        const float* rsR = (const float*)(smem + L_RS);
        for (int cc = 0; cc < 4; ++cc) {
            short8 fv[4], fvc[4];
            const float* wv0  = Wv  + (size_t)(8 * (l >> 4)) * HID + 64 * w + 16 * cc + d;
            const float* wvc0 = Wvc + (size_t)(8 * (l >> 4)) * HID + 64 * w + 16 * cc + d;
            #pragma unroll
            for (int kt = 0; kt < 4; ++kt)
                #pragma unroll
                for (int j = 0; j < 8; ++j) {
                    int o = (32 * kt + j) * HID;
                    fv[kt][j]  = f2bf(wv0[o]);
                    fvc[kt][j] = f2bf(wvc0[o]);
                }
            const int n = 64 * w + 16 * cc + d;
            const float bvn = bv[n], bvcn = bvc[n], gn = lng[n], bbn = lnb[n];
            float ctx = 0.f;
            for (int rt = 0; rt < NRT; ++rt) {
                short8 a[4];
                #pragma unroll
                for (int kt = 0; kt < 4; ++kt)
                    a[kt] = *(const short8*)(smem + L_XF + (((rt * 4 + kt) * 64 + l) << 4));
                f32x4 acc1 = fzero, acc2 = fzero;
                #pragma unroll
                for (int kt = 0; kt < 4; ++kt) {
                    acc1 = MFMA_B16(a[kt], fv[kt],  acc1);
                    acc2 = MFMA_B16(a[kt], fvc[kt], acc2);
                }
                #pragma unroll
                for (int r = 0; r < 4; ++r) {
                    int row = rt * 16 + 4 * g + r;
                    if (row < S_SZ) {
                        float vout = (acc1[r] + bvn) * sigm(acc2[r] + bvcn);
                        float pw = pr[w * SPAD + row];
                        ctx += pw * ((vout - muR[row]) * rsR[row] * gn + bbn);
                    }
                }
            }
            ctx += __shfl_xor(ctx, 16);
            ctx += __shfl_xor(ctx, 32);
            if (l < 16)
                out[(size_t)b * HID + 64 * w + 16 * cc + l] = ctx;
        }
    }
}

extern "C" void kernel_launch(void* const* d_in, const int* in_sizes, int n_in,
                              void* d_out, int out_size, void* d_ws, size_t ws_size,
                              hipStream_t stream)
{
    const int*   posid = (const int*)d_in[0];
    const float* qcv   = (const float*)d_in[1];
    const float* mask  = (const float*)d_in[2];
    const float* pe    = (const float*)d_in[3];
    const float* Wq    = (const float*)d_in[4];
    const float* bq    = (const float*)d_in[5];
    const float* Wqc   = (const float*)d_in[6];
    const float* bqc   = (const float*)d_in[7];
    const float* Wk    = (const float*)d_in[8];
    const float* bk    = (const float*)d_in[9];
    const float* Wkc   = (const float*)d_in[10];
    const float* bkc   = (const float*)d_in[11];
    const float* Wv    = (const float*)d_in[12];
    const float* bv    = (const float*)d_in[13];
    const float* Wvc   = (const float*)d_in[14];
    const float* bvc   = (const float*)d_in[15];
    const float* lng   = (const float*)d_in[16];
    const float* lnb   = (const float*)d_in[17];
    float* outp = (float*)d_out;

    hipFuncSetAttribute((const void*)attseq_main,
                        hipFuncAttributeMaxDynamicSharedMemorySize, L_TOTAL);

    attseq_main<<<B_SZ, 512, L_TOTAL, stream>>>(posid, qcv, mask, pe, Wq, bq, Wqc, bqc,
                                                Wk, bk, Wkc, bkc, Wv, bv, Wvc, bvc,
                                                lng, lnb, outp);
}